// Round 4
// baseline (181.353 us; speedup 1.0000x reference)
//
#include <hip/hip_runtime.h>
#include <hip/hip_bf16.h>

#define IS 256
#define NEARV 0.1f
#define FARV 100.0f
#define SLICES 32
#define NTILES 256                 // 16x16 tiles of 16x16 pixels
#define NITEMS (NTILES * SLICES)   // 8192 work items
#define NBLOCKS 2048

// ---------------- kernel 1: prep ----------------
// - clears the z-buffer (d_out used directly: raw float bits, atomicMin'd;
//   positive floats compare identically as uints) to 100.0f = FAR
// - zeroes the work-pop counter
// - builds one 64B record per face (threads 0..nf-1): gather 3 vertices,
//   transform (identical arithmetic to rounds 1-3, all absmax 0.0), cull.
//   Culled faces get a sentinel bbox that can never overlap a tile, so the
//   raster scans a FIXED range [0,nf) -- no compaction atomic needed.
// Per-face data (16 floats): x0,y0,x1,y1 | x2,y2,inv_area,iz0 | iz1,iz2,_,_ | xmin,ymin,xmax,ymax
__global__ void kprep(const float* __restrict__ verts, const int* __restrict__ faces,
                      float* __restrict__ fd, unsigned int* __restrict__ zb,
                      int* __restrict__ work, int nf) {
    int i = blockIdx.x * 256 + threadIdx.x;
    zb[i] = 0x42C80000u;  // __float_as_uint(100.0f); grid == IS*IS exactly
    if (i == 0) *work = 0;
    if (i >= nf) return;
    int i0 = faces[i * 3 + 0];
    int i1 = faces[i * 3 + 1];
    int i2 = faces[i * 3 + 2];
    // transform (v - eye; R == I exactly in fp32 for this camera)
    float z0 = verts[i0 * 3 + 2] + 2.7320508075688772f;
    float z1 = verts[i1 * 3 + 2] + 2.7320508075688772f;
    float z2 = verts[i2 * 3 + 2] + 2.7320508075688772f;
    bool front = (z0 > NEARV) && (z1 > NEARV) && (z2 > NEARV);
    float zs0 = (fabsf(z0) < 1e-5f) ? 1e-5f : z0;
    float zs1 = (fabsf(z1) < 1e-5f) ? 1e-5f : z1;
    float zs2 = (fabsf(z2) < 1e-5f) ? 1e-5f : z2;
    float d0 = zs0 * 0.57735026918962576f;  // zs * tan(30 deg)
    float d1 = zs1 * 0.57735026918962576f;
    float d2 = zs2 * 0.57735026918962576f;
    float x0 = verts[i0 * 3 + 0] / d0;
    float y0 = verts[i0 * 3 + 1] / d0;
    float x1 = verts[i1 * 3 + 0] / d1;
    float y1 = verts[i1 * 3 + 1] / d1;
    float x2 = verts[i2 * 3 + 0] / d2;
    float y2 = verts[i2 * 3 + 1] / d2;
    float area = (x1 - x0) * (y2 - y0) - (x2 - x0) * (y1 - y0);
    float4* o = (float4*)(fd + (size_t)i * 16);
    if (front && (fabsf(area) > 1e-8f)) {
        float xmin = fminf(x0, fminf(x1, x2));
        float xmax = fmaxf(x0, fmaxf(x1, x2));
        float ymin = fminf(y0, fminf(y1, y2));
        float ymax = fmaxf(y0, fmaxf(y1, y2));
        float ia = 1.0f / area;  // |area| > 1e-8 so area_s == area
        float iz0 = 1.0f / fmaxf(z0, 1e-4f);
        float iz1 = 1.0f / fmaxf(z1, 1e-4f);
        float iz2 = 1.0f / fmaxf(z2, 1e-4f);
        o[0] = make_float4(x0, y0, x1, y1);
        o[1] = make_float4(x2, y2, ia, iz0);
        o[2] = make_float4(iz1, iz2, 0.0f, 0.0f);
        o[3] = make_float4(xmin, ymin, xmax, ymax);
    } else {
        // sentinel: bbox.xmin > any px_hi -> never survives the tile test
        o[3] = make_float4(3.0e8f, 3.0e8f, -3.0e8f, -3.0e8f);
    }
}

// ---------------- kernel 2: persistent dynamic raster ----------------
// 2048 persistent blocks pop (tile, slice) items from a global counter
// (self-balancing; the hottest center tile is split across 32 slices).
// Per item: coalesced bbox scan of the slice's ~157-face range of fd,
// compact survivors into LDS, then all 256 pixel-threads evaluate the
// compacted list (uniform-address ds_read_b128 broadcasts); track
// max(inv_zc) (== min depth) in a register, one atomicMin per covered pixel.
__launch_bounds__(256)
__global__ void kraster(const float* __restrict__ fd, unsigned int* __restrict__ zb,
                        int* __restrict__ work, int nf) {
    __shared__ __align__(16) float sf[256 * 12];
    __shared__ int scount;
    __shared__ int sitem;

    const int tid = threadIdx.x;
    const int tx = tid & 15;
    const int ty = tid >> 4;
    const int per = (nf + SLICES - 1) / SLICES;  // 157 for nf=5000

    for (;;) {
        if (tid == 0) sitem = atomicAdd(work, 1);
        __syncthreads();  // also protects sf reuse: no wave can still be in the
                          // previous item's inner loop once all pass this barrier
        const int item = sitem;
        if (item >= NITEMS) break;  // block-uniform
        // item & 255 = tile: hot center tiles pop early across many blocks,
        // and concurrent blocks walk face ranges that share L2.
        const int tile = item & (NTILES - 1);
        const int slice = item >> 8;
        const int bx = tile & 15;
        const int by = tile >> 4;
        const int j = bx * 16 + tx;
        const int i = by * 16 + ty;
        // pixel centers: (2*idx + 1 - 256)/256 (exact in fp32)
        const float px = ((float)(2 * j + 1) - 256.0f) * (1.0f / 256.0f);
        const float py = ((float)(2 * i + 1) - 256.0f) * (1.0f / 256.0f);
        const float px_lo = ((float)(2 * (bx * 16) + 1) - 256.0f) * (1.0f / 256.0f);
        const float px_hi = px_lo + 30.0f / 256.0f;
        const float py_lo = ((float)(2 * (by * 16) + 1) - 256.0f) * (1.0f / 256.0f);
        const float py_hi = py_lo + 30.0f / 256.0f;

        const int f0 = slice * per;
        const int f1 = min(nf, f0 + per);

        float maxinv = 0.0f;

        for (int base = f0; base < f1; base += 256) {  // block-uniform trip count
            if (tid == 0) scount = 0;
            __syncthreads();
            int f = base + tid;
            if (f < f1) {
                const float4* p = (const float4*)(fd + (size_t)f * 16);
                float4 bb = p[3];
                if (bb.x <= px_hi && bb.z >= px_lo && bb.y <= py_hi && bb.w >= py_lo) {
                    float4 q0 = p[0];
                    float4 q1 = p[1];
                    float4 q2 = p[2];
                    int k = atomicAdd(&scount, 1);
                    float4* q = (float4*)(sf + k * 12);  // 48B stride, 16B aligned
                    q[0] = q0;
                    q[1] = q1;
                    q[2] = q2;
                }
            }
            __syncthreads();
            const int m = scount;
#pragma unroll 2
            for (int k = 0; k < m; ++k) {
                const float4* q = (const float4*)(sf + k * 12);  // uniform addr -> broadcast
                float4 a0 = q[0];
                float4 a1 = q[1];
                float4 a2 = q[2];
                float dx0 = a0.x - px, dy0 = a0.y - py;
                float dx1 = a0.z - px, dy1 = a0.w - py;
                float dx2 = a1.x - px, dy2 = a1.y - py;
                float e0 = dx1 * dy2 - dx2 * dy1;
                float e1 = dx2 * dy0 - dx0 * dy2;
                float w0 = e0 * a1.z;
                float w1 = e1 * a1.z;
                float w2 = 1.0f - w0 - w1;
                float invz = w0 * a1.w + w1 * a2.x + w2 * a2.y;
                float invzc = fmaxf(invz, 1e-6f);
                // zp = 1/invzc; valid iff inside && NEAR < zp < FAR <=> 0.01 < invzc < 10
                bool ok = (w0 >= 0.0f) && (w1 >= 0.0f) && (w2 >= 0.0f) &&
                          (invzc < 10.0f) && (invzc > 0.01f);
                if (ok) maxinv = fmaxf(maxinv, invzc);
            }
            // next chunk's reset+barrier (or next item's pop barrier) protects sf
        }
        if (maxinv > 0.0f) {
            float zp = 1.0f / maxinv;  // correctly-rounded 1/x is monotone => min-exact
            atomicMin(&zb[i * IS + j], __float_as_uint(zp));
        }
    }
}

extern "C" void kernel_launch(void* const* d_in, const int* in_sizes, int n_in,
                              void* d_out, int out_size, void* d_ws, size_t ws_size,
                              hipStream_t stream) {
    const float* verts = (const float*)d_in[0];
    const int* faces = (const int*)d_in[1];
    unsigned int* zb = (unsigned int*)d_out;  // float bits, min'd in place

    const int nf = in_sizes[1] / 3;  // 5000

    char* ws = (char*)d_ws;
    int* work = (int*)ws;                 // @0: pop counter
    float* fd = (float*)(ws + 256);       // nf * 64 B face records

    kprep<<<(IS * IS) / 256, 256, 0, stream>>>(verts, faces, fd, zb, work, nf);
    kraster<<<NBLOCKS, 256, 0, stream>>>(fd, zb, work, nf);
}

// Round 5
// 155.611 us; speedup vs baseline: 1.1654x; 1.1654x over previous
//
#include <hip/hip_runtime.h>
#include <hip/hip_bf16.h>

#define IS 256
#define NEARV 0.1f
#define FARV 100.0f
#define SLICES 128                 // 40 faces per slice (nf=5000)
#define NTILES 256                 // 16x16 tiles of 16x16 pixels
#define NITEMS (NTILES * SLICES)   // 32768 wave-items
#define NBLOCKS 1024
#define NWAVES (NBLOCKS * 4)       // 4096 waves -> 8 items per wave

// ---------------- kernel 1: prep ----------------
// - clears the z-buffer (d_out used directly: raw float bits, atomicMin'd;
//   positive floats compare identically as uints) to 100.0f = FAR
// - builds one 64B record per face: gather 3 vertices, transform (identical
//   arithmetic to rounds 1-4, all absmax 0.0), cull. Culled faces get a
//   sentinel bbox that can never overlap a tile -> raster scans fixed ranges.
// Per-face float4s: [x0,y0,x1,y1] [x2,y2,inv_area,iz0] [iz1,iz2,_,_] [xmin,ymin,xmax,ymax]
__global__ void kprep(const float* __restrict__ verts, const int* __restrict__ faces,
                      float4* __restrict__ fd, unsigned int* __restrict__ zb, int nf) {
    int i = blockIdx.x * 256 + threadIdx.x;
    zb[i] = 0x42C80000u;  // __float_as_uint(100.0f); grid == IS*IS exactly
    if (i >= nf) return;
    int i0 = faces[i * 3 + 0];
    int i1 = faces[i * 3 + 1];
    int i2 = faces[i * 3 + 2];
    // transform (v - eye; R == I exactly in fp32 for this camera)
    float z0 = verts[i0 * 3 + 2] + 2.7320508075688772f;
    float z1 = verts[i1 * 3 + 2] + 2.7320508075688772f;
    float z2 = verts[i2 * 3 + 2] + 2.7320508075688772f;
    bool front = (z0 > NEARV) && (z1 > NEARV) && (z2 > NEARV);
    float zs0 = (fabsf(z0) < 1e-5f) ? 1e-5f : z0;
    float zs1 = (fabsf(z1) < 1e-5f) ? 1e-5f : z1;
    float zs2 = (fabsf(z2) < 1e-5f) ? 1e-5f : z2;
    float d0 = zs0 * 0.57735026918962576f;  // zs * tan(30 deg)
    float d1 = zs1 * 0.57735026918962576f;
    float d2 = zs2 * 0.57735026918962576f;
    float x0 = verts[i0 * 3 + 0] / d0;
    float y0 = verts[i0 * 3 + 1] / d0;
    float x1 = verts[i1 * 3 + 0] / d1;
    float y1 = verts[i1 * 3 + 1] / d1;
    float x2 = verts[i2 * 3 + 0] / d2;
    float y2 = verts[i2 * 3 + 1] / d2;
    float area = (x1 - x0) * (y2 - y0) - (x2 - x0) * (y1 - y0);
    float4* o = fd + (size_t)i * 4;
    if (front && (fabsf(area) > 1e-8f)) {
        float xmin = fminf(x0, fminf(x1, x2));
        float xmax = fmaxf(x0, fmaxf(x1, x2));
        float ymin = fminf(y0, fminf(y1, y2));
        float ymax = fmaxf(y0, fmaxf(y1, y2));
        float ia = 1.0f / area;  // |area| > 1e-8 so area_s == area
        float iz0 = 1.0f / fmaxf(z0, 1e-4f);
        float iz1 = 1.0f / fmaxf(z1, 1e-4f);
        float iz2 = 1.0f / fmaxf(z2, 1e-4f);
        o[0] = make_float4(x0, y0, x1, y1);
        o[1] = make_float4(x2, y2, ia, iz0);
        o[2] = make_float4(iz1, iz2, 0.0f, 0.0f);
        o[3] = make_float4(xmin, ymin, xmax, ymax);
    } else {
        // sentinel: xmin > any px_hi -> never survives the tile test
        o[3] = make_float4(3.0e8f, 3.0e8f, -3.0e8f, -3.0e8f);
    }
}

// ---------------- kernel 2: wave-parallel raster ----------------
// One WAVE per (tile, slice) item: no LDS, no barriers, no shared state.
// Each lane owns 4 pixels of the 16x16 tile (col = lane&15, rows ry+4r).
// Per face: 4 broadcast float4 loads (L1 same-line, issued unconditionally so
// they pipeline across the unroll), wave-uniform bbox skip (s_cbranch_vccz),
// then ~95 VALU of 4-way-ILP pixel math. Items are statically interleaved so
// one wave's 8 serial items land on 8 different tiles (hot center tiles --
// which nearly every face overlaps -- spread across many waves).
__launch_bounds__(256)
__global__ void kraster(const float4* __restrict__ fd, unsigned int* __restrict__ zb, int nf) {
    const int wid = blockIdx.x * 4 + (threadIdx.x >> 6);
    const int lane = threadIdx.x & 63;
    const int cx = lane & 15;   // column within tile
    const int ry = lane >> 4;   // row base; lane handles rows ry + {0,4,8,12}
    const int per = (nf + SLICES - 1) / SLICES;  // 40

    for (int it = wid; it < NITEMS; it += NWAVES) {
        const int tile = it >> 7;               // it / SLICES
        const int slice = it & (SLICES - 1);
        const int bx = tile & 15;
        const int by = tile >> 4;
        const int j = bx * 16 + cx;
        // pixel centers: (2*idx + 1 - 256)/256 (exact in fp32)
        const float px = ((float)(2 * j + 1) - 256.0f) * (1.0f / 256.0f);
        float py[4];
#pragma unroll
        for (int r = 0; r < 4; ++r) {
            int row = by * 16 + ry + 4 * r;
            py[r] = ((float)(2 * row + 1) - 256.0f) * (1.0f / 256.0f);
        }
        const float px_lo = ((float)(2 * (bx * 16) + 1) - 256.0f) * (1.0f / 256.0f);
        const float px_hi = px_lo + 30.0f / 256.0f;
        const float py_lo = ((float)(2 * (by * 16) + 1) - 256.0f) * (1.0f / 256.0f);
        const float py_hi = py_lo + 30.0f / 256.0f;

        const int f0 = slice * per;
        const int f1 = min(nf, f0 + per);

        float mx[4] = {0.0f, 0.0f, 0.0f, 0.0f};

#pragma unroll 2
        for (int f = f0; f < f1; ++f) {
            const float4* p = fd + (size_t)f * 4;
            float4 bb = p[3];   // unconditional loads: pipeline across iterations
            float4 a0 = p[0];
            float4 a1 = p[1];
            float4 a2 = p[2];
            // wave-uniform values -> s_cbranch_vccz skip for non-overlapping faces
            if (bb.x <= px_hi && bb.z >= px_lo && bb.y <= py_hi && bb.w >= py_lo) {
                float dx0 = a0.x - px, dx1 = a0.z - px, dx2 = a1.x - px;
#pragma unroll
                for (int r = 0; r < 4; ++r) {
                    float dy0 = a0.y - py[r], dy1 = a0.w - py[r], dy2 = a1.y - py[r];
                    float e0 = dx1 * dy2 - dx2 * dy1;
                    float e1 = dx2 * dy0 - dx0 * dy2;
                    float w0 = e0 * a1.z;
                    float w1 = e1 * a1.z;
                    float w2 = 1.0f - w0 - w1;
                    float invz = w0 * a1.w + w1 * a2.x + w2 * a2.y;
                    float invzc = fmaxf(invz, 1e-6f);
                    // zp = 1/invzc; valid iff inside && NEAR < zp < FAR <=> 0.01 < invzc < 10
                    bool ok = (w0 >= 0.0f) && (w1 >= 0.0f) && (w2 >= 0.0f) &&
                              (invzc < 10.0f) && (invzc > 0.01f);
                    if (ok) mx[r] = fmaxf(mx[r], invzc);
                }
            }
        }
#pragma unroll
        for (int r = 0; r < 4; ++r) {
            if (mx[r] > 0.0f) {
                int row = by * 16 + ry + 4 * r;
                float zp = 1.0f / mx[r];  // correctly-rounded 1/x is monotone => min-exact
                atomicMin(&zb[row * IS + j], __float_as_uint(zp));
            }
        }
    }
}

extern "C" void kernel_launch(void* const* d_in, const int* in_sizes, int n_in,
                              void* d_out, int out_size, void* d_ws, size_t ws_size,
                              hipStream_t stream) {
    const float* verts = (const float*)d_in[0];
    const int* faces = (const int*)d_in[1];
    unsigned int* zb = (unsigned int*)d_out;  // float bits, min'd in place

    const int nf = in_sizes[1] / 3;  // 5000

    float4* fd = (float4*)d_ws;  // nf * 64 B face records

    kprep<<<(IS * IS) / 256, 256, 0, stream>>>(verts, faces, fd, zb, nf);
    kraster<<<NBLOCKS, 256, 0, stream>>>(fd, zb, nf);
}

// Round 6
// 109.253 us; speedup vs baseline: 1.6599x; 1.4243x over previous
//
#include <hip/hip_runtime.h>
#include <hip/hip_bf16.h>

#define IS 256
#define NEARV 0.1f
#define FARV 100.0f
#define NTX 16                    // 16x16 tiles of 16x16 px
#define NTILES 256
#define CAP 5120                  // per-tile list capacity >= nf -> overflow impossible
#define CHK 32                    // entries per raster work item
#define BINTH 128                 // threads per binning block
#define RBLOCKS 2048
#define RWAVES (RBLOCKS * 4)
#define MAXITEMS (NTILES * ((CAP + CHK - 1) / CHK))

// ---------------- kernel 1: prep ----------------
// - z-buffer (d_out directly; raw float bits, atomicMin'd; positive floats
//   compare as uints) init to 100.0f = FAR
// - zero per-tile counts + nitems
// - one 64B record per face: gather, transform, cull (arithmetic identical to
//   rounds 1-5, all absmax 0.0). Culled faces get a sentinel bbox that can
//   never pass the overlap predicate -> never enters any tile list.
// float4s: [x0,y0,x1,y1] [x2,y2,inv_area,iz0] [iz1,iz2,_,_] [xmin,ymin,xmax,ymax]
__global__ void kprep(const float* __restrict__ verts, const int* __restrict__ faces,
                      float4* __restrict__ fd, unsigned int* __restrict__ zb,
                      int* __restrict__ count, int* __restrict__ nitems, int nf) {
    int i = blockIdx.x * 256 + threadIdx.x;
    zb[i] = 0x42C80000u;  // __float_as_uint(100.0f); grid == IS*IS exactly
    if (i < NTILES) count[i] = 0;
    if (i == NTILES) *nitems = 0;
    if (i >= nf) return;
    int i0 = faces[i * 3 + 0];
    int i1 = faces[i * 3 + 1];
    int i2 = faces[i * 3 + 2];
    // transform (v - eye; R == I exactly in fp32 for this camera)
    float z0 = verts[i0 * 3 + 2] + 2.7320508075688772f;
    float z1 = verts[i1 * 3 + 2] + 2.7320508075688772f;
    float z2 = verts[i2 * 3 + 2] + 2.7320508075688772f;
    bool front = (z0 > NEARV) && (z1 > NEARV) && (z2 > NEARV);
    float zs0 = (fabsf(z0) < 1e-5f) ? 1e-5f : z0;
    float zs1 = (fabsf(z1) < 1e-5f) ? 1e-5f : z1;
    float zs2 = (fabsf(z2) < 1e-5f) ? 1e-5f : z2;
    float d0 = zs0 * 0.57735026918962576f;  // zs * tan(30 deg)
    float d1 = zs1 * 0.57735026918962576f;
    float d2 = zs2 * 0.57735026918962576f;
    float x0 = verts[i0 * 3 + 0] / d0;
    float y0 = verts[i0 * 3 + 1] / d0;
    float x1 = verts[i1 * 3 + 0] / d1;
    float y1 = verts[i1 * 3 + 1] / d1;
    float x2 = verts[i2 * 3 + 0] / d2;
    float y2 = verts[i2 * 3 + 1] / d2;
    float area = (x1 - x0) * (y2 - y0) - (x2 - x0) * (y1 - y0);
    float4* o = fd + (size_t)i * 4;
    if (front && (fabsf(area) > 1e-8f)) {
        float xmin = fminf(x0, fminf(x1, x2));
        float xmax = fmaxf(x0, fmaxf(x1, x2));
        float ymin = fminf(y0, fminf(y1, y2));
        float ymax = fmaxf(y0, fmaxf(y1, y2));
        float ia = 1.0f / area;  // |area| > 1e-8 so area_s == area
        float iz0 = 1.0f / fmaxf(z0, 1e-4f);
        float iz1 = 1.0f / fmaxf(z1, 1e-4f);
        float iz2 = 1.0f / fmaxf(z2, 1e-4f);
        o[0] = make_float4(x0, y0, x1, y1);
        o[1] = make_float4(x2, y2, ia, iz0);
        o[2] = make_float4(iz1, iz2, 0.0f, 0.0f);
        o[3] = make_float4(xmin, ymin, xmax, ymax);
    } else {
        // sentinel bbox: fails the overlap predicate for every tile
        o[3] = make_float4(3.0e8f, 3.0e8f, -3.0e8f, -3.0e8f);
    }
}

// ---------------- kernel 2: bin faces into per-tile lists ----------------
// Two-level counting: LDS aggregation per block, ONE global atomicAdd per
// (block, tile) to grab a contiguous range (avoids the 15ns/op same-address
// global-atomic serialization that capped rounds 3/4 at ~128us).
// Tile k x-overlap predicate (exact, same dyadic constants as the raster's
// old test): bb.x <= (32k-225)/256 && bb.z >= (32k-255)/256. The k-range is
// computed conservatively (+/-1) in float then the exact predicate is
// re-tested, so per-tile face sets are bit-identical to rounds 1-5.
__global__ void kbin(const float4* __restrict__ fd, int* __restrict__ count,
                     unsigned short* __restrict__ list, int nf) {
    __shared__ int scnt[NTILES];
    __shared__ int sbase[NTILES];
    const int tid = threadIdx.x;
    for (int t = tid; t < NTILES; t += BINTH) scnt[t] = 0;
    __syncthreads();
    const int f = blockIdx.x * BINTH + tid;
    int kx0 = 0, kx1 = -1, ky0 = 0, ky1 = -1;
    float4 bb = make_float4(0.f, 0.f, 0.f, 0.f);
    if (f < nf) {
        bb = fd[(size_t)f * 4 + 3];
        float tminx = fminf(fmaxf((bb.x * 256.0f + 225.0f) * (1.0f / 32.0f), -2.0f), 17.0f);
        float tmaxx = fminf(fmaxf((bb.z * 256.0f + 255.0f) * (1.0f / 32.0f), -2.0f), 17.0f);
        float tminy = fminf(fmaxf((bb.y * 256.0f + 225.0f) * (1.0f / 32.0f), -2.0f), 17.0f);
        float tmaxy = fminf(fmaxf((bb.w * 256.0f + 255.0f) * (1.0f / 32.0f), -2.0f), 17.0f);
        kx0 = max(0, (int)ceilf(tminx) - 1);
        kx1 = min(NTX - 1, (int)floorf(tmaxx) + 1);
        ky0 = max(0, (int)ceilf(tminy) - 1);
        ky1 = min(NTX - 1, (int)floorf(tmaxy) + 1);
    }
    // pass A: count
    for (int ky = ky0; ky <= ky1; ++ky) {
        float py_lo = (float)(32 * ky - 255) * (1.0f / 256.0f);
        float py_hi = (float)(32 * ky - 225) * (1.0f / 256.0f);
        if (!(bb.y <= py_hi && bb.w >= py_lo)) continue;
        for (int kx = kx0; kx <= kx1; ++kx) {
            float px_lo = (float)(32 * kx - 255) * (1.0f / 256.0f);
            float px_hi = (float)(32 * kx - 225) * (1.0f / 256.0f);
            if (bb.x <= px_hi && bb.z >= px_lo) atomicAdd(&scnt[ky * NTX + kx], 1);
        }
    }
    __syncthreads();
    for (int t = tid; t < NTILES; t += BINTH) {
        int c = scnt[t];
        sbase[t] = (c > 0) ? atomicAdd(&count[t], c) : 0;
        scnt[t] = 0;  // reuse as per-block cursor
    }
    __syncthreads();
    // pass B: scatter (order within a tile list is irrelevant: min is commutative)
    for (int ky = ky0; ky <= ky1; ++ky) {
        float py_lo = (float)(32 * ky - 255) * (1.0f / 256.0f);
        float py_hi = (float)(32 * ky - 225) * (1.0f / 256.0f);
        if (!(bb.y <= py_hi && bb.w >= py_lo)) continue;
        for (int kx = kx0; kx <= kx1; ++kx) {
            float px_lo = (float)(32 * kx - 255) * (1.0f / 256.0f);
            float px_hi = (float)(32 * kx - 225) * (1.0f / 256.0f);
            if (bb.x <= px_hi && bb.z >= px_lo) {
                int t = ky * NTX + kx;
                int slot = sbase[t] + atomicAdd(&scnt[t], 1);
                list[(size_t)t * CAP + slot] = (unsigned short)f;
            }
        }
    }
}

// ---------------- kernel 3: build compacted item list (no atomics) ----------------
// item = (tile << 16) | chunk, tile-major. Raster wave i takes item i, so a hot
// tile's ~125 consecutive chunks land on ~125 consecutive waves (distinct
// blocks/CUs) -- perfect static balance with zero pop contention.
__global__ void kitems(const int* __restrict__ count, int* __restrict__ items,
                       int* __restrict__ nitems) {
    __shared__ int snch[NTILES];
    __shared__ int soff[NTILES];
    const int t = threadIdx.x;  // one block, 256 threads
    int c = count[t];
    snch[t] = (c + CHK - 1) / CHK;
    __syncthreads();
    if (t == 0) {
        int run = 0;
        for (int i = 0; i < NTILES; ++i) { soff[i] = run; run += snch[i]; }
        *nitems = run;
    }
    __syncthreads();
    int off = soff[t];
    int n = snch[t];
    for (int k = 0; k < n; ++k) items[off + k] = (t << 16) | k;
}

// ---------------- kernel 4: raster ----------------
// One wave per item: 16x16 tile, 4 px/lane (col = lane&15, rows ry+4r), <=32
// pre-matched entries. No bbox tests, no barriers, no LDS, no pops. Per entry:
// 1 uniform ushort + 3 uniform float4 loads (L1), ~95 VALU of 4-way-ILP pixel
// math (expression-identical to rounds 1-5). One atomicMin per covered pixel.
__launch_bounds__(256)
__global__ void kraster(const float4* __restrict__ fd, const unsigned short* __restrict__ list,
                        const int* __restrict__ count, const int* __restrict__ items,
                        const int* __restrict__ nitems, unsigned int* __restrict__ zb) {
    const int wid = blockIdx.x * 4 + (threadIdx.x >> 6);
    const int lane = threadIdx.x & 63;
    const int cx = lane & 15;
    const int ry = lane >> 4;
    const int ni = *nitems;

    for (int it = wid; it < ni; it += RWAVES) {
        const int pk = items[it];
        const int tile = pk >> 16;
        const int chunk = pk & 0xffff;
        const int bx = tile & 15;
        const int by = tile >> 4;
        const int j = bx * 16 + cx;
        const float px = ((float)(2 * j + 1) - 256.0f) * (1.0f / 256.0f);
        float py[4];
        int row[4];
#pragma unroll
        for (int r = 0; r < 4; ++r) {
            row[r] = by * 16 + ry + 4 * r;
            py[r] = ((float)(2 * row[r] + 1) - 256.0f) * (1.0f / 256.0f);
        }
        const int s = chunk * CHK;
        const int n = min(CHK, count[tile] - s);
        const unsigned short* lp = list + (size_t)tile * CAP + s;

        float mx[4] = {0.0f, 0.0f, 0.0f, 0.0f};

#pragma unroll 2
        for (int e = 0; e < n; ++e) {
            const int fidx = lp[e];                       // uniform -> one L1 line
            const float4* p = fd + (size_t)fidx * 4;
            float4 a0 = p[0];
            float4 a1 = p[1];
            float4 a2 = p[2];
            float dx0 = a0.x - px, dx1 = a0.z - px, dx2 = a1.x - px;
#pragma unroll
            for (int r = 0; r < 4; ++r) {
                float dy0 = a0.y - py[r], dy1 = a0.w - py[r], dy2 = a1.y - py[r];
                float e0 = dx1 * dy2 - dx2 * dy1;
                float e1 = dx2 * dy0 - dx0 * dy2;
                float w0 = e0 * a1.z;
                float w1 = e1 * a1.z;
                float w2 = 1.0f - w0 - w1;
                float invz = w0 * a1.w + w1 * a2.x + w2 * a2.y;
                float invzc = fmaxf(invz, 1e-6f);
                // zp = 1/invzc; valid iff inside && NEAR < zp < FAR <=> 0.01 < invzc < 10
                bool ok = (w0 >= 0.0f) && (w1 >= 0.0f) && (w2 >= 0.0f) &&
                          (invzc < 10.0f) && (invzc > 0.01f);
                if (ok) mx[r] = fmaxf(mx[r], invzc);
            }
        }
#pragma unroll
        for (int r = 0; r < 4; ++r) {
            if (mx[r] > 0.0f) {
                float zp = 1.0f / mx[r];  // correctly-rounded 1/x is monotone => min-exact
                atomicMin(&zb[row[r] * IS + j], __float_as_uint(zp));
            }
        }
    }
}

extern "C" void kernel_launch(void* const* d_in, const int* in_sizes, int n_in,
                              void* d_out, int out_size, void* d_ws, size_t ws_size,
                              hipStream_t stream) {
    const float* verts = (const float*)d_in[0];
    const int* faces = (const int*)d_in[1];
    unsigned int* zb = (unsigned int*)d_out;  // float bits, min'd in place

    const int nf = in_sizes[1] / 3;  // 5000 (< CAP and < 65536: ushort indices ok)

    char* ws = (char*)d_ws;
    size_t off = 0;
    float4* fd = (float4*)(ws + off);            off += (size_t)nf * 64;          // 320 KB
    off = (off + 255) & ~(size_t)255;
    int* count = (int*)(ws + off);               off += NTILES * 4;               // 1 KB
    off = (off + 255) & ~(size_t)255;
    int* nitems = (int*)(ws + off);              off += 256;
    int* items = (int*)(ws + off);               off += (size_t)MAXITEMS * 4;     // 160 KB
    off = (off + 255) & ~(size_t)255;
    unsigned short* list = (unsigned short*)(ws + off);  // 256*5120*2 = 2.62 MB

    kprep<<<(IS * IS) / 256, 256, 0, stream>>>(verts, faces, fd, zb, count, nitems, nf);
    kbin<<<(nf + BINTH - 1) / BINTH, BINTH, 0, stream>>>(fd, count, list, nf);
    kitems<<<1, 256, 0, stream>>>(count, items, nitems);
    kraster<<<RBLOCKS, 256, 0, stream>>>(fd, list, count, items, nitems, zb);
}